// Round 1
// baseline (269.451 us; speedup 1.0000x reference)
//
#include <hip/hip_runtime.h>
#include <math.h>

#define N 2048
#define BATCH 16

// ---------------------------------------------------------------------------
// Kernel 1: Bsum[b][j] = sum_k |s[b][j] - s[b][k]|
// grid = BATCH*16 blocks, 128 threads; each block stages the full 2048-float
// score row in LDS (8 KB) and computes 128 j's.
// ---------------------------------------------------------------------------
__global__ __launch_bounds__(128) void bsum_kernel(const float* __restrict__ scores,
                                                   float* __restrict__ dsum) {
    __shared__ float s_sh[N];
    const int b = blockIdx.x >> 4;           // 16 blocks per batch
    const int jBase = (blockIdx.x & 15) * 128;
    const float* s = scores + (size_t)b * N;

    for (int t = threadIdx.x; t < N / 4; t += 128) {
        ((float4*)s_sh)[t] = ((const float4*)s)[t];
    }
    __syncthreads();

    const int j = jBase + threadIdx.x;
    const float sj = s_sh[j];
    float acc = 0.f;
#pragma unroll 8
    for (int k = 0; k < N / 4; ++k) {
        float4 v = ((const float4*)s_sh)[k];   // broadcast read: conflict-free
        acc += fabsf(sj - v.x) + fabsf(sj - v.y) + fabsf(sj - v.z) + fabsf(sj - v.w);
    }
    dsum[(size_t)b * N + j] = acc;
}

// ---------------------------------------------------------------------------
// Kernel 2: P_hat[b][i][j] = softmax_j( scaling[i]*s[j] - Bsum[j] )
// One wave (64 lanes) per output row i. 4 waves per block; block stages s[]
// and Bsum[] for its batch in LDS (16 KB). Each lane holds 32 logits in
// registers; wave shfl-reduce for max and sum; coalesced float4 stores.
// grid = BATCH * (N/4) = 8192 blocks of 256 threads.
// ---------------------------------------------------------------------------
__global__ __launch_bounds__(256) void softmax_kernel(const float* __restrict__ scores,
                                                      const float* __restrict__ dsum,
                                                      float* __restrict__ out) {
    __shared__ float s_sh[N];
    __shared__ float d_sh[N];

    const int blocksPerBatch = N / 4;                  // 512
    const int b = blockIdx.x / blocksPerBatch;
    const int blockRow = blockIdx.x % blocksPerBatch;  // 0..511

    const float* s = scores + (size_t)b * N;
    const float* dd = dsum + (size_t)b * N;

    for (int t = threadIdx.x; t < N / 4; t += 256) {
        ((float4*)s_sh)[t] = ((const float4*)s)[t];
        ((float4*)d_sh)[t] = ((const float4*)dd)[t];
    }
    __syncthreads();

    const int wave = threadIdx.x >> 6;
    const int lane = threadIdx.x & 63;
    const int row = blockRow * 4 + wave;               // i in [0, 2048)
    const float c = (float)(N - 1 - 2 * row);          // scaling[i]

    float lg[32];
    float m = -INFINITY;
#pragma unroll
    for (int it = 0; it < 8; ++it) {
        const int idx = it * 64 + lane;                // float4 index
        float4 s4 = ((const float4*)s_sh)[idx];
        float4 d4 = ((const float4*)d_sh)[idx];
        float l0 = fmaf(c, s4.x, -d4.x);
        float l1 = fmaf(c, s4.y, -d4.y);
        float l2 = fmaf(c, s4.z, -d4.z);
        float l3 = fmaf(c, s4.w, -d4.w);
        lg[it * 4 + 0] = l0;
        lg[it * 4 + 1] = l1;
        lg[it * 4 + 2] = l2;
        lg[it * 4 + 3] = l3;
        m = fmaxf(m, fmaxf(fmaxf(l0, l1), fmaxf(l2, l3)));
    }
#pragma unroll
    for (int off = 32; off > 0; off >>= 1)
        m = fmaxf(m, __shfl_xor(m, off, 64));

    float sum = 0.f;
#pragma unroll
    for (int k = 0; k < 32; ++k) {
        lg[k] = __expf(lg[k] - m);
        sum += lg[k];
    }
#pragma unroll
    for (int off = 32; off > 0; off >>= 1)
        sum += __shfl_xor(sum, off, 64);

    const float inv = 1.0f / sum;

    float* orow = out + (((size_t)b * N) + row) * N;
#pragma unroll
    for (int it = 0; it < 8; ++it) {
        const int idx = it * 64 + lane;                // float4 index -> j = 4*idx
        float4 o;
        o.x = lg[it * 4 + 0] * inv;
        o.y = lg[it * 4 + 1] * inv;
        o.z = lg[it * 4 + 2] * inv;
        o.w = lg[it * 4 + 3] * inv;
        ((float4*)orow)[idx] = o;
    }
}

extern "C" void kernel_launch(void* const* d_in, const int* in_sizes, int n_in,
                              void* d_out, int out_size, void* d_ws, size_t ws_size,
                              hipStream_t stream) {
    const float* scores = (const float*)d_in[0];
    float* out = (float*)d_out;
    float* dsum = (float*)d_ws;   // BATCH*N floats = 128 KB scratch

    bsum_kernel<<<BATCH * 16, 128, 0, stream>>>(scores, dsum);
    softmax_kernel<<<BATCH * (N / 4), 256, 0, stream>>>(scores, dsum, out);
}